// Round 1
// baseline (793.615 us; speedup 1.0000x reference)
//
#include <hip/hip_runtime.h>
#include <stdint.h>
#include <stddef.h>

#define NHEADS 16
#define QLORA  1536
#define KVLORA 512
#define QKH    192
#define VH     128
#define BB     2
#define SS     1024
#define MROWS  (BB*SS)   // 2048
#define HID    3072

typedef __attribute__((ext_vector_type(4))) float fx4;
typedef __attribute__((ext_vector_type(4))) short sx4;
typedef __attribute__((ext_vector_type(8))) short sx8;

__device__ __forceinline__ short f2bf(float f) {
  uint32_t u = __builtin_bit_cast(uint32_t, f);
  u = (u + 0x7fffu + ((u >> 16) & 1u)) >> 16;
  return (short)u;
}
__device__ __forceinline__ float bf2f(short s) {
  uint32_t u = ((uint32_t)(uint16_t)s) << 16;
  return __builtin_bit_cast(float, u);
}
__device__ __forceinline__ void gl_lds16(const void* g, void* l) {
  __builtin_amdgcn_global_load_lds((const __attribute__((address_space(1))) void*)g,
                                   (__attribute__((address_space(3))) void*)l, 16, 0, 0);
}
// Load an 8-elem MFMA A/B fragment: two 4-elem k-blocks at p and p+16 shorts.
__device__ __forceinline__ sx8 ldfrag(const short* p) {
  sx4 lo = *(const sx4*)p;
  sx4 hi = *(const sx4*)(p + 16);
  sx8 r;
  r[0]=lo[0]; r[1]=lo[1]; r[2]=lo[2]; r[3]=lo[3];
  r[4]=hi[0]; r[5]=hi[1]; r[6]=hi[2]; r[7]=hi[3];
  return r;
}

// ---------------- fp32 -> bf16 convert (vectorized x4) ----------------
__global__ void k_cvt(const float* __restrict__ in, short* __restrict__ out, int n4) {
  int stride = gridDim.x * blockDim.x;
  for (int i = blockIdx.x * blockDim.x + threadIdx.x; i < n4; i += stride) {
    fx4 v = *(const fx4*)(in + (size_t)i * 4);
    sx4 o;
    o[0] = f2bf(v[0]); o[1] = f2bf(v[1]); o[2] = f2bf(v[2]); o[3] = f2bf(v[3]);
    *(sx4*)(out + (size_t)i * 4) = o;
  }
}

// ---------------- rope cos/sin table: tab[pos][32][2] ----------------
__global__ void k_rope_tab(float* __restrict__ tab) {
  int i = blockIdx.x * blockDim.x + threadIdx.x;
  if (i >= SS * 32) return;
  int pos = i >> 5, fi = i & 31;
  float inv = powf(10000.0f, -(float)fi / 32.0f);
  float ang = (float)pos * inv;
  tab[i * 2]     = cosf(ang);
  tab[i * 2 + 1] = sinf(ang);
}

// ---------------- GEMM: C[m][n] = sum_k A[m][k]*Bt[n][k] + bias[n] ----------------
// A: M x K bf16, Bt: N x K bf16. 128x128 tile, BK=32, 4 waves, mfma 16x16x32 bf16.
template <int OUT_BF16>
__global__ __launch_bounds__(256, 2)
void k_gemm_bt(const short* __restrict__ A, const short* __restrict__ Bt,
               const float* __restrict__ bias, void* __restrict__ Cv,
               int M, int N, int K) {
  __shared__ short As[128 * 32];
  __shared__ short Bs[128 * 32];
  const int tid  = threadIdx.x;
  const int lane = tid & 63;
  const int g    = lane >> 4;
  const int r16  = lane & 15;
  const int wave = tid >> 6;
  const int wm   = (wave >> 1) * 64;
  const int wn   = (wave & 1) * 64;
  const int m0   = blockIdx.x * 128;
  const int n0   = blockIdx.y * 128;

  fx4 acc[4][4] = {};

  for (int kk = 0; kk < K; kk += 32) {
#pragma unroll
    for (int i = 0; i < 2; ++i) {
      int c = tid + 256 * i;
      int row = c >> 2;
      int k0  = (c & 3) * 8;
      int am = m0 + row; if (am > M - 1) am = M - 1;
      int bn = n0 + row; if (bn > N - 1) bn = N - 1;
      gl_lds16(A  + (size_t)am * K + kk + k0, &As[c * 8]);
      gl_lds16(Bt + (size_t)bn * K + kk + k0, &Bs[c * 8]);
    }
    __syncthreads();

    sx8 af[4], bfv[4];
#pragma unroll
    for (int mi = 0; mi < 4; ++mi)
      af[mi] = ldfrag(&As[(wm + mi * 16 + r16) * 32 + 4 * g]);
#pragma unroll
    for (int ni = 0; ni < 4; ++ni)
      bfv[ni] = ldfrag(&Bs[(wn + ni * 16 + r16) * 32 + 4 * g]);
#pragma unroll
    for (int mi = 0; mi < 4; ++mi)
#pragma unroll
      for (int ni = 0; ni < 4; ++ni)
        acc[mi][ni] = __builtin_amdgcn_mfma_f32_16x16x32_bf16(af[mi], bfv[ni], acc[mi][ni], 0, 0, 0);
    __syncthreads();
  }

#pragma unroll
  for (int mi = 0; mi < 4; ++mi) {
    int mbase = m0 + wm + mi * 16 + 4 * g;
#pragma unroll
    for (int ni = 0; ni < 4; ++ni) {
      int ncol = n0 + wn + ni * 16 + r16;
      if (ncol < N) {
        float bv = bias[ncol];
#pragma unroll
        for (int r = 0; r < 4; ++r) {
          int mr = mbase + r;
          if (mr < M) {
            float v = acc[mi][ni][r] + bv;
            if (OUT_BF16) ((short*)Cv)[(size_t)mr * N + ncol] = f2bf(v);
            else          ((float*)Cv)[(size_t)mr * N + ncol] = v;
          }
        }
      }
    }
  }
}

// ---------------- RMSNorm row kernel (bf16 in/out, fp32 weight) ----------------
__global__ __launch_bounds__(256)
void k_rmsnorm(const short* __restrict__ x, const float* __restrict__ w,
               short* __restrict__ out, int L, int xstride) {
  int row = blockIdx.x;
  const short* xr = x + (size_t)row * xstride;
  short* orow = out + (size_t)row * L;
  int nch = L >> 3;
  float ssq = 0.f;
  for (int c = threadIdx.x; c < nch; c += 256) {
    sx8 v = *(const sx8*)(xr + c * 8);
#pragma unroll
    for (int j = 0; j < 8; ++j) { float f = bf2f(v[j]); ssq += f * f; }
  }
#pragma unroll
  for (int o = 32; o >= 1; o >>= 1) ssq += __shfl_xor(ssq, o, 64);
  __shared__ float red[4];
  if ((threadIdx.x & 63) == 0) red[threadIdx.x >> 6] = ssq;
  __syncthreads();
  float tot = red[0] + red[1] + red[2] + red[3];
  float rs = 1.0f / sqrtf(tot / (float)L + 1e-6f);
  for (int c = threadIdx.x; c < nch; c += 256) {
    sx8 v = *(const sx8*)(xr + c * 8);
    sx8 o;
#pragma unroll
    for (int j = 0; j < 8; ++j) o[j] = f2bf(bf2f(v[j]) * rs * w[c * 8 + j]);
    *(sx8*)(orow + c * 8) = o;
  }
}

// ---------------- RoPE on q (in place, cols 128..191 of each head) ----------------
__global__ void k_rope_q(short* __restrict__ q, const float* __restrict__ tab) {
  int p = blockIdx.x * blockDim.x + threadIdx.x;
  if (p >= MROWS * NHEADS * 32) return;
  int i = p & 31;
  int h = (p >> 5) & 15;
  int row = p >> 9;
  int pos = row & (SS - 1);
  size_t base = (((size_t)row * NHEADS + h) * QKH) + 128 + 2 * i;
  float c = tab[(pos * 32 + i) * 2], s = tab[(pos * 32 + i) * 2 + 1];
  float x1 = bf2f(q[base]), x2 = bf2f(q[base + 1]);
  q[base]     = f2bf(x1 * c - x2 * s);
  q[base + 1] = f2bf(x1 * s + x2 * c);
}

// ---------------- RoPE on k_rope (kv cols 512..575 -> kr[row][64]) ----------------
__global__ void k_rope_k(const short* __restrict__ kv, short* __restrict__ kr,
                         const float* __restrict__ tab) {
  int p = blockIdx.x * blockDim.x + threadIdx.x;
  if (p >= MROWS * 32) return;
  int i = p & 31;
  int row = p >> 5;
  int pos = row & (SS - 1);
  float c = tab[(pos * 32 + i) * 2], s = tab[(pos * 32 + i) * 2 + 1];
  float x1 = bf2f(kv[(size_t)row * 576 + 512 + 2 * i]);
  float x2 = bf2f(kv[(size_t)row * 576 + 512 + 2 * i + 1]);
  kr[(size_t)row * 64 + 2 * i]     = f2bf(x1 * c - x2 * s);
  kr[(size_t)row * 64 + 2 * i + 1] = f2bf(x1 * s + x2 * c);
}

// ---------------- assemble K: kb[b][h][t][192] = {kvb nope | kr broadcast} ----------------
__global__ void k_build_k(const short* __restrict__ kvb, const short* __restrict__ kr,
                          short* __restrict__ kb) {
  int c = blockIdx.x * blockDim.x + threadIdx.x;
  if (c >= MROWS * NHEADS * 24) return;
  int i = c % 24;
  int h = (c / 24) & 15;
  int row = c / 384;
  int b = row >> 10, t = row & (SS - 1);
  sx8 v;
  if (i < 16) v = *(const sx8*)(kvb + (size_t)row * 4096 + h * 256 + i * 8);
  else        v = *(const sx8*)(kr  + (size_t)row * 64 + (i - 16) * 8);
  *(sx8*)(kb + (((size_t)(b * NHEADS + h) * SS + t) * QKH) + i * 8) = v;
}

// ---------------- transpose V: vt[b][h][d][t] from kvb[row][h*256+128+d] ----------------
__global__ __launch_bounds__(256)
void k_vt(const short* __restrict__ kvb, short* __restrict__ vt) {
  int bh = blockIdx.x;
  int t0 = blockIdx.y * 64;
  int b = bh >> 4, h = bh & 15;
  __shared__ short sm[64 * 128];
  int tid = threadIdx.x;
#pragma unroll
  for (int i = 0; i < 4; ++i) {
    int c = tid + 256 * i;
    int tt = c >> 4, d0 = (c & 15) * 8;
    sx8 v = *(const sx8*)(kvb + ((size_t)(b * SS + t0 + tt)) * 4096 + h * 256 + 128 + d0);
    *(sx8*)(sm + tt * 128 + d0) = v;
  }
  __syncthreads();
#pragma unroll
  for (int i = 0; i < 4; ++i) {
    int c = tid + 256 * i;
    int d = c >> 3, tof = (c & 7) * 8;
    sx8 v;
#pragma unroll
    for (int j = 0; j < 8; ++j) v[j] = sm[(tof + j) * 128 + d];
    *(sx8*)(vt + ((size_t)bh * VH + d) * SS + t0 + tof) = v;
  }
}

// ---------------- fused causal attention (flash-style, swapped QK^T) ----------------
__global__ __launch_bounds__(256, 2)
void k_attn(const short* __restrict__ q, const short* __restrict__ kb,
            const short* __restrict__ vt, short* __restrict__ ao) {
  const int bh = blockIdx.x;
  const int b = bh >> 4, h = bh & 15;
  const int qt0 = blockIdx.y * 64;
  const int tid = threadIdx.x;
  const int lane = tid & 63;
  const int wave = tid >> 6;
  const int g = lane >> 4, r16 = lane & 15;
  const int qg = qt0 + wave * 16 + r16;   // this lane's q row

  __shared__ short Ks[32 * QKH];   // 12 KB
  __shared__ short Vs[VH * 32];    // 8 KB  (Vt rows: [d][t])

  // Q fragments (B-operand), kept in registers across all k-tiles
  sx8 qf[6];
  {
    const short* qr = q + (((size_t)(b * SS + qg)) * NHEADS + h) * QKH;
#pragma unroll
    for (int f = 0; f < 6; ++f) qf[f] = ldfrag(qr + f * 32 + 4 * g);
  }

  float mrun = -1e30f, lrun = 0.0f;
  fx4 oacc[8] = {};
  const float scale = 0.07216878364870323f;   // 1/sqrt(192)

  const int ntiles = qt0 / 32 + 2;            // covers t0 <= qt0+63
  for (int kt = 0; kt < ntiles; ++kt) {
    int t0 = kt * 32;
    // stage K tile: 32 rows x 192
#pragma unroll
    for (int i = 0; i < 3; ++i) {
      int c = tid + 256 * i;
      int row = c / 24, k0 = (c % 24) * 8;
      gl_lds16(kb + (((size_t)bh * SS) + t0 + row) * QKH + k0, &Ks[c * 8]);
    }
    // stage Vt tile: 128 rows(d) x 32(t)
#pragma unroll
    for (int i = 0; i < 2; ++i) {
      int c = tid + 256 * i;
      int d = c >> 2, tof = (c & 3) * 8;
      gl_lds16(vt + ((size_t)bh * VH + d) * SS + t0 + tof, &Vs[c * 8]);
    }
    __syncthreads();

    // QK^T (swapped): S^T[t][q], two 16-t halves
    fx4 sacc[2] = {};
#pragma unroll
    for (int th = 0; th < 2; ++th)
#pragma unroll
      for (int f = 0; f < 6; ++f) {
        sx8 kf = ldfrag(&Ks[(th * 16 + r16) * QKH + f * 32 + 4 * g]);
        sacc[th] = __builtin_amdgcn_mfma_f32_16x16x32_bf16(kf, qf[f], sacc[th], 0, 0, 0);
      }

    // scale + causal mask + online softmax
    float pv[8];
    float tmax = -1e30f;
#pragma unroll
    for (int th = 0; th < 2; ++th)
#pragma unroll
      for (int r = 0; r < 4; ++r) {
        int t = t0 + th * 16 + 4 * g + r;
        float s = sacc[th][r] * scale + ((t <= qg) ? 0.0f : -1000000000.0f);
        pv[th * 4 + r] = s;
        tmax = fmaxf(tmax, s);
      }
    tmax = fmaxf(tmax, __shfl_xor(tmax, 16, 64));
    tmax = fmaxf(tmax, __shfl_xor(tmax, 32, 64));
    float mnew = fmaxf(mrun, tmax);
    float corr = __expf(mrun - mnew);
    float psum = 0.f;
#pragma unroll
    for (int j = 0; j < 8; ++j) { pv[j] = __expf(pv[j] - mnew); psum += pv[j]; }
    psum += __shfl_xor(psum, 16, 64);
    psum += __shfl_xor(psum, 32, 64);
    lrun = lrun * corr + psum;
    mrun = mnew;
#pragma unroll
    for (int f8 = 0; f8 < 8; ++f8) oacc[f8] *= corr;

    // P fragment (B-operand of PV) — lane-local, no shuffles
    sx8 pf;
#pragma unroll
    for (int j = 0; j < 8; ++j) pf[j] = f2bf(pv[j]);

    // PV: O^T[d][q] += Vt(d x t) * P^T(t x q)
#pragma unroll
    for (int f8 = 0; f8 < 8; ++f8) {
      sx8 vf = ldfrag(&Vs[(f8 * 16 + r16) * 32 + 4 * g]);
      oacc[f8] = __builtin_amdgcn_mfma_f32_16x16x32_bf16(vf, pf, oacc[f8], 0, 0, 0);
    }
    __syncthreads();
  }

  float inv = 1.0f / lrun;
#pragma unroll
  for (int f8 = 0; f8 < 8; ++f8)
#pragma unroll
    for (int r = 0; r < 4; ++r) {
      int d = f8 * 16 + 4 * g + r;
      ao[(((size_t)(b * SS + qg)) * NHEADS + h) * VH + d] = f2bf(oacc[f8][r] * inv);
    }
}

// ---------------- launcher ----------------
extern "C" void kernel_launch(void* const* d_in, const int* in_sizes, int n_in,
                              void* d_out, int out_size, void* d_ws, size_t ws_size,
                              hipStream_t stream) {
  const float* hs       = (const float*)d_in[0];
  const float* wq_a_w   = (const float*)d_in[2];
  const float* wq_a_b   = (const float*)d_in[3];
  const float* q_norm_w = (const float*)d_in[4];
  const float* wq_b_w   = (const float*)d_in[5];
  const float* wq_b_b   = (const float*)d_in[6];
  const float* wkv_a_w  = (const float*)d_in[7];
  const float* wkv_a_b  = (const float*)d_in[8];
  const float* kv_norm_w= (const float*)d_in[9];
  const float* wkv_b_w  = (const float*)d_in[10];
  const float* wkv_b_b  = (const float*)d_in[11];
  const float* wo_w     = (const float*)d_in[12];
  const float* wo_b     = (const float*)d_in[13];
  float* out = (float*)d_out;

  // workspace layout (shorts unless noted)
  short* ws0 = (short*)d_ws;
  size_t off = 0;
  short* wqa_bf  = ws0 + off; off += (size_t)QLORA * HID;        // 1536x3072
  short* wqb_bf  = ws0 + off; off += (size_t)HID * QLORA;        // 3072x1536
  short* wkva_bf = ws0 + off; off += (size_t)576 * HID;          // 576x3072
  short* wkvb_bf = ws0 + off; off += (size_t)4096 * KVLORA;      // 4096x512
  short* wo_bf   = ws0 + off; off += (size_t)HID * 2048;         // 3072x2048
  short* h_bf    = ws0 + off; off += (size_t)MROWS * HID;
  short* qlat    = ws0 + off; off += (size_t)MROWS * QLORA;
  short* qn      = ws0 + off; off += (size_t)MROWS * QLORA;
  short* qb      = ws0 + off; off += (size_t)MROWS * HID;        // [row][h][192]
  short* kv      = ws0 + off; off += (size_t)MROWS * 576;
  short* kr      = ws0 + off; off += (size_t)MROWS * 64;
  short* kvn     = ws0 + off; off += (size_t)MROWS * KVLORA;
  short* kvb     = ws0 + off; off += (size_t)MROWS * 4096;
  short* kfull   = ws0 + off; off += (size_t)BB * NHEADS * SS * QKH;
  short* vtb     = ws0 + off; off += (size_t)BB * NHEADS * VH * SS;
  short* ao      = ws0 + off; off += (size_t)MROWS * 2048;
  float* tab     = (float*)(ws0 + off + (off & 1));              // align to 4B

  // 1) bf16 conversions
  k_cvt<<<2048, 256, 0, stream>>>(wq_a_w,  wqa_bf,  (int)((size_t)QLORA * HID / 4));
  k_cvt<<<2048, 256, 0, stream>>>(wq_b_w,  wqb_bf,  (int)((size_t)HID * QLORA / 4));
  k_cvt<<<2048, 256, 0, stream>>>(wkv_a_w, wkva_bf, (int)((size_t)576 * HID / 4));
  k_cvt<<<2048, 256, 0, stream>>>(wkv_b_w, wkvb_bf, (int)((size_t)4096 * KVLORA / 4));
  k_cvt<<<2048, 256, 0, stream>>>(wo_w,    wo_bf,   (int)((size_t)HID * 2048 / 4));
  k_cvt<<<2048, 256, 0, stream>>>(hs,      h_bf,    (int)((size_t)MROWS * HID / 4));
  k_rope_tab<<<(SS * 32 + 255) / 256, 256, 0, stream>>>(tab);

  // 2) q path
  k_gemm_bt<1><<<dim3(MROWS / 128, QLORA / 128), 256, 0, stream>>>(h_bf, wqa_bf, wq_a_b, qlat, MROWS, QLORA, HID);
  k_rmsnorm<<<MROWS, 256, 0, stream>>>(qlat, q_norm_w, qn, QLORA, QLORA);
  k_gemm_bt<1><<<dim3(MROWS / 128, HID / 128), 256, 0, stream>>>(qn, wqb_bf, wq_b_b, qb, MROWS, HID, QLORA);
  k_rope_q<<<(MROWS * NHEADS * 32 + 255) / 256, 256, 0, stream>>>(qb, tab);

  // 3) kv path
  k_gemm_bt<1><<<dim3(MROWS / 128, (576 + 127) / 128), 256, 0, stream>>>(h_bf, wkva_bf, wkv_a_b, kv, MROWS, 576, HID);
  k_rope_k<<<(MROWS * 32 + 255) / 256, 256, 0, stream>>>(kv, kr, tab);
  k_rmsnorm<<<MROWS, 256, 0, stream>>>(kv, kv_norm_w, kvn, KVLORA, 576);
  k_gemm_bt<1><<<dim3(MROWS / 128, 4096 / 128), 256, 0, stream>>>(kvn, wkvb_bf, wkv_b_b, kvb, MROWS, 4096, KVLORA);
  k_build_k<<<(MROWS * NHEADS * 24 + 255) / 256, 256, 0, stream>>>(kvb, kr, kfull);
  k_vt<<<dim3(BB * NHEADS, SS / 64), 256, 0, stream>>>(kvb, vtb);

  // 4) attention
  k_attn<<<dim3(BB * NHEADS, SS / 64), 256, 0, stream>>>(qb, kfull, vtb, ao);

  // 5) output projection (fp32 out)
  k_gemm_bt<0><<<dim3(MROWS / 128, HID / 128), 256, 0, stream>>>(ao, wo_bf, wo_b, out, MROWS, HID, 2048);
}

// Round 2
// 379.310 us; speedup vs baseline: 2.0923x; 2.0923x over previous
//
#include <hip/hip_runtime.h>
#include <stdint.h>
#include <stddef.h>

#define NHEADS 16
#define QLORA  1536
#define KVLORA 512
#define QKH    192
#define VH     128
#define BB     2
#define SS     1024
#define MROWS  (BB*SS)   // 2048
#define HID    3072

typedef __attribute__((ext_vector_type(4))) float fx4;
typedef __attribute__((ext_vector_type(4))) short sx4;
typedef __attribute__((ext_vector_type(8))) short sx8;

__device__ __forceinline__ short f2bf(float f) {
  uint32_t u = __builtin_bit_cast(uint32_t, f);
  u = (u + 0x7fffu + ((u >> 16) & 1u)) >> 16;
  return (short)u;
}
__device__ __forceinline__ float bf2f(short s) {
  uint32_t u = ((uint32_t)(uint16_t)s) << 16;
  return __builtin_bit_cast(float, u);
}
__device__ __forceinline__ void gl_lds16(const void* g, void* l) {
  __builtin_amdgcn_global_load_lds((const __attribute__((address_space(1))) void*)g,
                                   (__attribute__((address_space(3))) void*)l, 16, 0, 0);
}
// Non-swizzled fragment load (for global memory): two 4-elem k-blocks at p, p+16.
__device__ __forceinline__ sx8 ldfrag(const short* p) {
  sx4 lo = *(const sx4*)p;
  sx4 hi = *(const sx4*)(p + 16);
  sx8 r;
  r[0]=lo[0]; r[1]=lo[1]; r[2]=lo[2]; r[3]=lo[3];
  r[4]=hi[0]; r[5]=hi[1]; r[6]=hi[2]; r[7]=hi[3];
  return r;
}
// Swizzled LDS fragment load. LDS conceptual layout: [row][rowShorts] with each
// 16B chunk c stored physically at chunk (c & ~7) | ((c&7) ^ (row&7)).
// Fragment: k = baseChunk*8 + {4g..4g+3, 16+4g..16+4g+3}  (baseChunk = 4*ksub or 4*f)
__device__ __forceinline__ sx8 ldfrag_swz(const short* lds, int row, int rowShorts,
                                          int baseChunk, int g) {
  const int r7 = row & 7;
  const int gh = g >> 1, lo4 = (g & 1) * 4;
  int ch0 = baseChunk + gh;
  int ch1 = baseChunk + 2 + gh;
  ch0 = (ch0 & ~7) | ((ch0 & 7) ^ r7);
  ch1 = (ch1 & ~7) | ((ch1 & 7) ^ r7);
  const short* base = lds + row * rowShorts;
  sx4 a = *(const sx4*)(base + ch0 * 8 + lo4);
  sx4 b = *(const sx4*)(base + ch1 * 8 + lo4);
  sx8 r;
  r[0]=a[0]; r[1]=a[1]; r[2]=a[2]; r[3]=a[3];
  r[4]=b[0]; r[5]=b[1]; r[6]=b[2]; r[7]=b[3];
  return r;
}

// ---------------- fp32 -> bf16 convert (vectorized x4) ----------------
__global__ void k_cvt(const float* __restrict__ in, short* __restrict__ out, int n4) {
  int stride = gridDim.x * blockDim.x;
  for (int i = blockIdx.x * blockDim.x + threadIdx.x; i < n4; i += stride) {
    fx4 v = *(const fx4*)(in + (size_t)i * 4);
    sx4 o;
    o[0] = f2bf(v[0]); o[1] = f2bf(v[1]); o[2] = f2bf(v[2]); o[3] = f2bf(v[3]);
    *(sx4*)(out + (size_t)i * 4) = o;
  }
}

// ---------------- rope cos/sin table: tab[pos][32][2] ----------------
__global__ void k_rope_tab(float* __restrict__ tab) {
  int i = blockIdx.x * blockDim.x + threadIdx.x;
  if (i >= SS * 32) return;
  int pos = i >> 5, fi = i & 31;
  float inv = powf(10000.0f, -(float)fi / 32.0f);
  float ang = (float)pos * inv;
  tab[i * 2]     = cosf(ang);
  tab[i * 2 + 1] = sinf(ang);
}

// ---------------- GEMM: C[m][n] = sum_k A[m][k]*Bt[n][k] + bias[n] ----------------
// 128x128 tile, BK=64, 4 waves, mfma 16x16x32 bf16, swizzled LDS (2-way max).
template <int OUT_BF16>
__global__ __launch_bounds__(256, 2)
void k_gemm_bt(const short* __restrict__ A, const short* __restrict__ Bt,
               const float* __restrict__ bias, void* __restrict__ Cv,
               int M, int N, int K) {
  __shared__ short As[128 * 64];   // 16 KB
  __shared__ short Bs[128 * 64];   // 16 KB
  const int tid  = threadIdx.x;
  const int lane = tid & 63;
  const int g    = lane >> 4;
  const int r16  = lane & 15;
  const int wave = tid >> 6;
  const int wm   = (wave >> 1) * 64;
  const int wn   = (wave & 1) * 64;
  const int m0   = blockIdx.x * 128;
  const int n0   = blockIdx.y * 128;

  fx4 acc[4][4] = {};

  for (int kk = 0; kk < K; kk += 64) {
#pragma unroll
    for (int i = 0; i < 4; ++i) {
      int cc  = tid + 256 * i;          // chunk id 0..1023
      int row = cc >> 3;
      int src = ((cc & 7) ^ (row & 7)) * 8;   // swizzled source chunk (shorts)
      int am = m0 + row; if (am > M - 1) am = M - 1;
      int bn = n0 + row; if (bn > N - 1) bn = N - 1;
      gl_lds16(A  + (size_t)am * K + kk + src, &As[cc * 8]);
      gl_lds16(Bt + (size_t)bn * K + kk + src, &Bs[cc * 8]);
    }
    __syncthreads();

#pragma unroll
    for (int s = 0; s < 2; ++s) {
      sx8 af[4], bfv[4];
#pragma unroll
      for (int mi = 0; mi < 4; ++mi)
        af[mi] = ldfrag_swz(As, wm + mi * 16 + r16, 64, s * 4, g);
#pragma unroll
      for (int ni = 0; ni < 4; ++ni)
        bfv[ni] = ldfrag_swz(Bs, wn + ni * 16 + r16, 64, s * 4, g);
#pragma unroll
      for (int mi = 0; mi < 4; ++mi)
#pragma unroll
        for (int ni = 0; ni < 4; ++ni)
          acc[mi][ni] = __builtin_amdgcn_mfma_f32_16x16x32_bf16(af[mi], bfv[ni], acc[mi][ni], 0, 0, 0);
    }
    __syncthreads();
  }

#pragma unroll
  for (int mi = 0; mi < 4; ++mi) {
    int mbase = m0 + wm + mi * 16 + 4 * g;
#pragma unroll
    for (int ni = 0; ni < 4; ++ni) {
      int ncol = n0 + wn + ni * 16 + r16;
      if (ncol < N) {
        float bv = bias[ncol];
#pragma unroll
        for (int r = 0; r < 4; ++r) {
          int mr = mbase + r;
          if (mr < M) {
            float v = acc[mi][ni][r] + bv;
            if (OUT_BF16) ((short*)Cv)[(size_t)mr * N + ncol] = f2bf(v);
            else          ((float*)Cv)[(size_t)mr * N + ncol] = v;
          }
        }
      }
    }
  }
}

// ---------------- RMSNorm row kernel (bf16 in/out, fp32 weight) ----------------
__global__ __launch_bounds__(256)
void k_rmsnorm(const short* __restrict__ x, const float* __restrict__ w,
               short* __restrict__ out, int L, int xstride) {
  int row = blockIdx.x;
  const short* xr = x + (size_t)row * xstride;
  short* orow = out + (size_t)row * L;
  int nch = L >> 3;
  float ssq = 0.f;
  for (int c = threadIdx.x; c < nch; c += 256) {
    sx8 v = *(const sx8*)(xr + c * 8);
#pragma unroll
    for (int j = 0; j < 8; ++j) { float f = bf2f(v[j]); ssq += f * f; }
  }
#pragma unroll
  for (int o = 32; o >= 1; o >>= 1) ssq += __shfl_xor(ssq, o, 64);
  __shared__ float red[4];
  if ((threadIdx.x & 63) == 0) red[threadIdx.x >> 6] = ssq;
  __syncthreads();
  float tot = red[0] + red[1] + red[2] + red[3];
  float rs = 1.0f / sqrtf(tot / (float)L + 1e-6f);
  for (int c = threadIdx.x; c < nch; c += 256) {
    sx8 v = *(const sx8*)(xr + c * 8);
    sx8 o;
#pragma unroll
    for (int j = 0; j < 8; ++j) o[j] = f2bf(bf2f(v[j]) * rs * w[c * 8 + j]);
    *(sx8*)(orow + c * 8) = o;
  }
}

// ---------------- RoPE on q (in place, cols 128..191 of each head) ----------------
__global__ void k_rope_q(short* __restrict__ q, const float* __restrict__ tab) {
  int p = blockIdx.x * blockDim.x + threadIdx.x;
  if (p >= MROWS * NHEADS * 32) return;
  int i = p & 31;
  int h = (p >> 5) & 15;
  int row = p >> 9;
  int pos = row & (SS - 1);
  size_t base = (((size_t)row * NHEADS + h) * QKH) + 128 + 2 * i;
  float c = tab[(pos * 32 + i) * 2], s = tab[(pos * 32 + i) * 2 + 1];
  float x1 = bf2f(q[base]), x2 = bf2f(q[base + 1]);
  q[base]     = f2bf(x1 * c - x2 * s);
  q[base + 1] = f2bf(x1 * s + x2 * c);
}

// ---------------- RoPE on k_rope (kv cols 512..575 -> kr[row][64]) ----------------
__global__ void k_rope_k(const short* __restrict__ kv, short* __restrict__ kr,
                         const float* __restrict__ tab) {
  int p = blockIdx.x * blockDim.x + threadIdx.x;
  if (p >= MROWS * 32) return;
  int i = p & 31;
  int row = p >> 5;
  int pos = row & (SS - 1);
  float c = tab[(pos * 32 + i) * 2], s = tab[(pos * 32 + i) * 2 + 1];
  float x1 = bf2f(kv[(size_t)row * 576 + 512 + 2 * i]);
  float x2 = bf2f(kv[(size_t)row * 576 + 512 + 2 * i + 1]);
  kr[(size_t)row * 64 + 2 * i]     = f2bf(x1 * c - x2 * s);
  kr[(size_t)row * 64 + 2 * i + 1] = f2bf(x1 * s + x2 * c);
}

// ---------------- transpose V: vt[b][h][d][t] from kvb[row][h*256+128+d] ----------------
__global__ __launch_bounds__(256)
void k_vt(const short* __restrict__ kvb, short* __restrict__ vt) {
  int bh = blockIdx.x;
  int t0 = blockIdx.y * 64;
  int b = bh >> 4, h = bh & 15;
  __shared__ short sm[64 * 128];
  int tid = threadIdx.x;
#pragma unroll
  for (int i = 0; i < 4; ++i) {
    int c = tid + 256 * i;
    int tt = c >> 4, d0 = (c & 15) * 8;
    sx8 v = *(const sx8*)(kvb + ((size_t)(b * SS + t0 + tt)) * 4096 + h * 256 + 128 + d0);
    *(sx8*)(sm + tt * 128 + d0) = v;
  }
  __syncthreads();
#pragma unroll
  for (int i = 0; i < 4; ++i) {
    int c = tid + 256 * i;
    int d = c >> 3, tof = (c & 7) * 8;
    sx8 v;
#pragma unroll
    for (int j = 0; j < 8; ++j) v[j] = sm[(tof + j) * 128 + d];
    *(sx8*)(vt + ((size_t)bh * VH + d) * SS + t0 + tof) = v;
  }
}

// ---------------- fused causal attention (flash-style, swapped QK^T) ----------------
// 64 q-rows/block (4 waves x 16), KT=64, K staged from kvb+kr, V from vt; swizzled LDS.
__global__ __launch_bounds__(256, 2)
void k_attn(const short* __restrict__ q, const short* __restrict__ kvb,
            const short* __restrict__ kr, const short* __restrict__ vt,
            short* __restrict__ ao) {
  const int bh = blockIdx.x;
  const int b = bh >> 4, h = bh & 15;
  const int qt0 = blockIdx.y * 64;
  const int tid = threadIdx.x;
  const int lane = tid & 63;
  const int wave = tid >> 6;
  const int g = lane >> 4, r16 = lane & 15;
  const int qg = qt0 + wave * 16 + r16;   // this lane's q row

  __shared__ short Ks[64 * QKH];   // 24 KB, swizzled rows of 24 chunks
  __shared__ short Vs[VH * 64];    // 16 KB, swizzled rows of 8 chunks ([d][t])

  // Q fragments (B-operand), kept in registers across all k-tiles
  sx8 qf[6];
  {
    const short* qr = q + (((size_t)(b * SS + qg)) * NHEADS + h) * QKH;
#pragma unroll
    for (int f = 0; f < 6; ++f) qf[f] = ldfrag(qr + f * 32 + 4 * g);
  }

  float mrun = -1e30f, lrun = 0.0f;
  fx4 oacc[8] = {};
  const float scale = 0.07216878364870323f;   // 1/sqrt(192)

  const int ntiles = qt0 / 64 + 1;
  for (int kt = 0; kt < ntiles; ++kt) {
    const int t0 = kt * 64;
    // stage K tile: 64 rows x 192 (24 chunks/row); nope from kvb, rope from kr
#pragma unroll
    for (int i = 0; i < 6; ++i) {
      int cc = tid + 256 * i;            // 0..1535
      int row = cc / 24, ch = cc % 24;
      int sc = (ch & 24) | ((ch & 7) ^ (row & 7));
      size_t grow = (size_t)(b * SS + t0 + row);
      const short* src = (sc < 16) ? kvb + grow * 4096 + h * 256 + sc * 8
                                   : kr + grow * 64 + (sc - 16) * 8;
      gl_lds16(src, &Ks[cc * 8]);
    }
    // stage Vt tile: 128 rows(d) x 64(t) (8 chunks/row)
#pragma unroll
    for (int i = 0; i < 4; ++i) {
      int cc = tid + 256 * i;            // 0..1023
      int row = cc >> 3;
      int sc = (cc & 7) ^ (row & 7);
      gl_lds16(vt + ((size_t)bh * VH + row) * SS + t0 + sc * 8, &Vs[cc * 8]);
    }
    __syncthreads();

    // QK^T (swapped): S^T[t][q], four 16-t groups
    const bool diag = (kt == ntiles - 1);
    float pv[16];
    float tmax = -1e30f;
#pragma unroll
    for (int th = 0; th < 4; ++th) {
      fx4 sacc = {};
#pragma unroll
      for (int f = 0; f < 6; ++f) {
        sx8 kf = ldfrag_swz(Ks, th * 16 + r16, QKH, f * 4, g);
        sacc = __builtin_amdgcn_mfma_f32_16x16x32_bf16(kf, qf[f], sacc, 0, 0, 0);
      }
#pragma unroll
      for (int r = 0; r < 4; ++r) {
        int t = t0 + th * 16 + 4 * g + r;
        float s = sacc[r] * scale;
        if (diag && t > qg) s = -1e30f;
        pv[th * 4 + r] = s;
        tmax = fmaxf(tmax, s);
      }
    }
    tmax = fmaxf(tmax, __shfl_xor(tmax, 16, 64));
    tmax = fmaxf(tmax, __shfl_xor(tmax, 32, 64));
    float mnew = fmaxf(mrun, tmax);
    float corr = __expf(mrun - mnew);
    float psum = 0.f;
#pragma unroll
    for (int j = 0; j < 16; ++j) { pv[j] = __expf(pv[j] - mnew); psum += pv[j]; }
    psum += __shfl_xor(psum, 16, 64);
    psum += __shfl_xor(psum, 32, 64);
    lrun = lrun * corr + psum;
    mrun = mnew;
#pragma unroll
    for (int f8 = 0; f8 < 8; ++f8) oacc[f8] *= corr;

    // P fragments (B-operand of PV), lane-local
    sx8 pf0, pf1;
#pragma unroll
    for (int j = 0; j < 8; ++j) { pf0[j] = f2bf(pv[j]); pf1[j] = f2bf(pv[8 + j]); }

    // PV: O^T[d][q] += Vt(d x t) * P^T(t x q), two t-substeps
#pragma unroll
    for (int f8 = 0; f8 < 8; ++f8) {
      sx8 v0 = ldfrag_swz(Vs, f8 * 16 + r16, 64, 0, g);
      sx8 v1 = ldfrag_swz(Vs, f8 * 16 + r16, 64, 4, g);
      oacc[f8] = __builtin_amdgcn_mfma_f32_16x16x32_bf16(v0, pf0, oacc[f8], 0, 0, 0);
      oacc[f8] = __builtin_amdgcn_mfma_f32_16x16x32_bf16(v1, pf1, oacc[f8], 0, 0, 0);
    }
    __syncthreads();
  }

  float inv = 1.0f / lrun;
#pragma unroll
  for (int f8 = 0; f8 < 8; ++f8)
#pragma unroll
    for (int r = 0; r < 4; ++r) {
      int d = f8 * 16 + 4 * g + r;
      ao[(((size_t)(b * SS + qg)) * NHEADS + h) * VH + d] = f2bf(oacc[f8][r] * inv);
    }
}

// ---------------- launcher ----------------
extern "C" void kernel_launch(void* const* d_in, const int* in_sizes, int n_in,
                              void* d_out, int out_size, void* d_ws, size_t ws_size,
                              hipStream_t stream) {
  const float* hs       = (const float*)d_in[0];
  const float* wq_a_w   = (const float*)d_in[2];
  const float* wq_a_b   = (const float*)d_in[3];
  const float* q_norm_w = (const float*)d_in[4];
  const float* wq_b_w   = (const float*)d_in[5];
  const float* wq_b_b   = (const float*)d_in[6];
  const float* wkv_a_w  = (const float*)d_in[7];
  const float* wkv_a_b  = (const float*)d_in[8];
  const float* kv_norm_w= (const float*)d_in[9];
  const float* wkv_b_w  = (const float*)d_in[10];
  const float* wkv_b_b  = (const float*)d_in[11];
  const float* wo_w     = (const float*)d_in[12];
  const float* wo_b     = (const float*)d_in[13];
  float* out = (float*)d_out;

  // workspace layout (shorts unless noted)
  short* ws0 = (short*)d_ws;
  size_t off = 0;
  short* wqa_bf  = ws0 + off; off += (size_t)QLORA * HID;
  short* wqb_bf  = ws0 + off; off += (size_t)HID * QLORA;
  short* wkva_bf = ws0 + off; off += (size_t)576 * HID;
  short* wkvb_bf = ws0 + off; off += (size_t)4096 * KVLORA;
  short* wo_bf   = ws0 + off; off += (size_t)HID * 2048;
  short* h_bf    = ws0 + off; off += (size_t)MROWS * HID;
  short* qlat    = ws0 + off; off += (size_t)MROWS * QLORA;
  short* qn      = ws0 + off; off += (size_t)MROWS * QLORA;
  short* qb      = ws0 + off; off += (size_t)MROWS * HID;        // [row][h][192]
  short* kv      = ws0 + off; off += (size_t)MROWS * 576;
  short* kr      = ws0 + off; off += (size_t)MROWS * 64;
  short* kvn     = ws0 + off; off += (size_t)MROWS * KVLORA;
  short* kvb     = ws0 + off; off += (size_t)MROWS * 4096;
  short* vtb     = ws0 + off; off += (size_t)BB * NHEADS * VH * SS;
  short* ao      = ws0 + off; off += (size_t)MROWS * 2048;
  float* tab     = (float*)(ws0 + off + (off & 1));

  // 1) bf16 conversions
  k_cvt<<<2048, 256, 0, stream>>>(wq_a_w,  wqa_bf,  (int)((size_t)QLORA * HID / 4));
  k_cvt<<<2048, 256, 0, stream>>>(wq_b_w,  wqb_bf,  (int)((size_t)HID * QLORA / 4));
  k_cvt<<<2048, 256, 0, stream>>>(wkv_a_w, wkva_bf, (int)((size_t)576 * HID / 4));
  k_cvt<<<2048, 256, 0, stream>>>(wkv_b_w, wkvb_bf, (int)((size_t)4096 * KVLORA / 4));
  k_cvt<<<2048, 256, 0, stream>>>(wo_w,    wo_bf,   (int)((size_t)HID * 2048 / 4));
  k_cvt<<<2048, 256, 0, stream>>>(hs,      h_bf,    (int)((size_t)MROWS * HID / 4));
  k_rope_tab<<<(SS * 32 + 255) / 256, 256, 0, stream>>>(tab);

  // 2) q path
  k_gemm_bt<1><<<dim3(MROWS / 128, QLORA / 128), 256, 0, stream>>>(h_bf, wqa_bf, wq_a_b, qlat, MROWS, QLORA, HID);
  k_rmsnorm<<<MROWS, 256, 0, stream>>>(qlat, q_norm_w, qn, QLORA, QLORA);
  k_gemm_bt<1><<<dim3(MROWS / 128, HID / 128), 256, 0, stream>>>(qn, wqb_bf, wq_b_b, qb, MROWS, HID, QLORA);
  k_rope_q<<<(MROWS * NHEADS * 32 + 255) / 256, 256, 0, stream>>>(qb, tab);

  // 3) kv path
  k_gemm_bt<1><<<dim3(MROWS / 128, (576 + 127) / 128), 256, 0, stream>>>(h_bf, wkva_bf, wkv_a_b, kv, MROWS, 576, HID);
  k_rope_k<<<(MROWS * 32 + 255) / 256, 256, 0, stream>>>(kv, kr, tab);
  k_rmsnorm<<<MROWS, 256, 0, stream>>>(kv, kv_norm_w, kvn, KVLORA, 576);
  k_gemm_bt<1><<<dim3(MROWS / 128, 4096 / 128), 256, 0, stream>>>(kvn, wkvb_bf, wkv_b_b, kvb, MROWS, 4096, KVLORA);
  k_vt<<<dim3(BB * NHEADS, SS / 64), 256, 0, stream>>>(kvb, vtb);

  // 4) attention (K assembled on the fly from kvb + kr)
  k_attn<<<dim3(BB * NHEADS, SS / 64), 256, 0, stream>>>(qb, kvb, kr, vtb, ao);

  // 5) output projection (fp32 out)
  k_gemm_bt<0><<<dim3(MROWS / 128, HID / 128), 256, 0, stream>>>(ao, wo_bf, wo_b, out, MROWS, HID, 2048);
}

// Round 3
// 275.773 us; speedup vs baseline: 2.8778x; 1.3754x over previous
//
#include <hip/hip_runtime.h>
#include <stdint.h>
#include <stddef.h>

#define NHEADS 16
#define QLORA  1536
#define KVLORA 512
#define QKH    192
#define VH     128
#define BB     2
#define SS     1024
#define MROWS  (BB*SS)   // 2048
#define HID    3072

typedef __attribute__((ext_vector_type(4))) float fx4;
typedef __attribute__((ext_vector_type(4))) short sx4;
typedef __attribute__((ext_vector_type(8))) short sx8;

__device__ __forceinline__ short f2bf(float f) {
  uint32_t u = __builtin_bit_cast(uint32_t, f);
  u = (u + 0x7fffu + ((u >> 16) & 1u)) >> 16;
  return (short)u;
}
__device__ __forceinline__ float bf2f(short s) {
  uint32_t u = ((uint32_t)(uint16_t)s) << 16;
  return __builtin_bit_cast(float, u);
}
__device__ __forceinline__ void gl_lds16(const void* g, void* l) {
  __builtin_amdgcn_global_load_lds((const __attribute__((address_space(1))) void*)g,
                                   (__attribute__((address_space(3))) void*)l, 16, 0, 0);
}
__device__ __forceinline__ sx8 ldfrag(const short* p) {
  sx4 lo = *(const sx4*)p;
  sx4 hi = *(const sx4*)(p + 16);
  sx8 r;
  r[0]=lo[0]; r[1]=lo[1]; r[2]=lo[2]; r[3]=lo[3];
  r[4]=hi[0]; r[5]=hi[1]; r[6]=hi[2]; r[7]=hi[3];
  return r;
}
// Swizzled LDS fragment load; chunk c of row stored at (c&~7)|((c&7)^(row&7)).
__device__ __forceinline__ sx8 ldfrag_swz(const short* lds, int row, int rowShorts,
                                          int baseChunk, int g) {
  const int r7 = row & 7;
  const int gh = g >> 1, lo4 = (g & 1) * 4;
  int ch0 = baseChunk + gh;
  int ch1 = baseChunk + 2 + gh;
  ch0 = (ch0 & ~7) | ((ch0 & 7) ^ r7);
  ch1 = (ch1 & ~7) | ((ch1 & 7) ^ r7);
  const short* base = lds + row * rowShorts;
  sx4 a = *(const sx4*)(base + ch0 * 8 + lo4);
  sx4 b = *(const sx4*)(base + ch1 * 8 + lo4);
  sx8 r;
  r[0]=a[0]; r[1]=a[1]; r[2]=a[2]; r[3]=a[3];
  r[4]=b[0]; r[5]=b[1]; r[6]=b[2]; r[7]=b[3];
  return r;
}

// ---------------- fp32 -> bf16 convert ----------------
__global__ void k_cvt(const float* __restrict__ in, short* __restrict__ out, int n4) {
  int stride = gridDim.x * blockDim.x;
  for (int i = blockIdx.x * blockDim.x + threadIdx.x; i < n4; i += stride) {
    fx4 v = *(const fx4*)(in + (size_t)i * 4);
    sx4 o;
    o[0] = f2bf(v[0]); o[1] = f2bf(v[1]); o[2] = f2bf(v[2]); o[3] = f2bf(v[3]);
    *(sx4*)(out + (size_t)i * 4) = o;
  }
}

// ---------------- rope cos/sin table ----------------
__global__ void k_rope_tab(float* __restrict__ tab) {
  int i = blockIdx.x * blockDim.x + threadIdx.x;
  if (i >= SS * 32) return;
  int pos = i >> 5, fi = i & 31;
  float inv = powf(10000.0f, -(float)fi / 32.0f);
  float ang = (float)pos * inv;
  tab[i * 2]     = cosf(ang);
  tab[i * 2 + 1] = sinf(ang);
}

// ---------------- dual-problem GEMM ----------------
// C[m][n] = sum_k A[m][k]*Bt[n][k] + bias[n].  Tile 64x128, BK=64, 4 waves
// (each 32x64), swizzled LDS, M must be 2048 (mt=32). Two problems per launch.
struct GemmProb {
  const short* A; const short* Bt; const float* bias; void* C;
  int N; int K; int outbf16;
};

__global__ __launch_bounds__(256, 4)
void k_gemm2(GemmProb p0, GemmProb p1, int nblk0) {
  // XCD-aware bijective swizzle (gridDim.x % 8 == 0 guaranteed by launcher)
  int nwg = gridDim.x;
  int bid = (blockIdx.x % 8) * (nwg >> 3) + (blockIdx.x >> 3);
  const GemmProb p = (bid < nblk0) ? p0 : p1;
  int lb = (bid < nblk0) ? bid : bid - nblk0;
  const int m0 = (lb & 31) * 64;       // M = 2048 -> 32 m-tiles
  const int n0 = (lb >> 5) * 128;

  __shared__ short As[64 * 64];    // 8 KB
  __shared__ short Bs[128 * 64];   // 16 KB
  const int tid  = threadIdx.x;
  const int lane = tid & 63;
  const int g    = lane >> 4;
  const int r16  = lane & 15;
  const int wave = tid >> 6;
  const int wm   = (wave >> 1) * 32;
  const int wn   = (wave & 1) * 64;
  const int N = p.N, K = p.K;

  fx4 acc[2][4] = {};

  for (int kk = 0; kk < K; kk += 64) {
#pragma unroll
    for (int i = 0; i < 2; ++i) {        // A: 512 chunks
      int cc  = tid + 256 * i;
      int row = cc >> 3;
      int src = ((cc & 7) ^ (row & 7)) * 8;
      gl_lds16(p.A + (size_t)(m0 + row) * K + kk + src, &As[cc * 8]);
    }
#pragma unroll
    for (int i = 0; i < 4; ++i) {        // B: 1024 chunks
      int cc  = tid + 256 * i;
      int row = cc >> 3;
      int src = ((cc & 7) ^ (row & 7)) * 8;
      int bn = n0 + row; if (bn > N - 1) bn = N - 1;
      gl_lds16(p.Bt + (size_t)bn * K + kk + src, &Bs[cc * 8]);
    }
    __syncthreads();

#pragma unroll
    for (int s = 0; s < 2; ++s) {
      sx8 af[2], bfv[4];
#pragma unroll
      for (int mi = 0; mi < 2; ++mi)
        af[mi] = ldfrag_swz(As, wm + mi * 16 + r16, 64, s * 4, g);
#pragma unroll
      for (int ni = 0; ni < 4; ++ni)
        bfv[ni] = ldfrag_swz(Bs, wn + ni * 16 + r16, 64, s * 4, g);
#pragma unroll
      for (int mi = 0; mi < 2; ++mi)
#pragma unroll
        for (int ni = 0; ni < 4; ++ni)
          acc[mi][ni] = __builtin_amdgcn_mfma_f32_16x16x32_bf16(af[mi], bfv[ni], acc[mi][ni], 0, 0, 0);
    }
    __syncthreads();
  }

  if (p.outbf16) {
#pragma unroll
    for (int mi = 0; mi < 2; ++mi) {
      int mbase = m0 + wm + mi * 16 + 4 * g;
#pragma unroll
      for (int ni = 0; ni < 4; ++ni) {
        int ncol = n0 + wn + ni * 16 + r16;
        if (ncol < N) {
          float bv = p.bias[ncol];
#pragma unroll
          for (int r = 0; r < 4; ++r)
            ((short*)p.C)[(size_t)(mbase + r) * N + ncol] = f2bf(acc[mi][ni][r] + bv);
        }
      }
    }
  } else {
#pragma unroll
    for (int mi = 0; mi < 2; ++mi) {
      int mbase = m0 + wm + mi * 16 + 4 * g;
#pragma unroll
      for (int ni = 0; ni < 4; ++ni) {
        int ncol = n0 + wn + ni * 16 + r16;
        if (ncol < N) {
          float bv = p.bias[ncol];
#pragma unroll
          for (int r = 0; r < 4; ++r)
            ((float*)p.C)[(size_t)(mbase + r) * N + ncol] = acc[mi][ni][r] + bv;
        }
      }
    }
  }
}

// ---------------- RMSNorm ----------------
__global__ __launch_bounds__(256)
void k_rmsnorm(const short* __restrict__ x, const float* __restrict__ w,
               short* __restrict__ out, int L, int xstride) {
  int row = blockIdx.x;
  const short* xr = x + (size_t)row * xstride;
  short* orow = out + (size_t)row * L;
  int nch = L >> 3;
  float ssq = 0.f;
  for (int c = threadIdx.x; c < nch; c += 256) {
    sx8 v = *(const sx8*)(xr + c * 8);
#pragma unroll
    for (int j = 0; j < 8; ++j) { float f = bf2f(v[j]); ssq += f * f; }
  }
#pragma unroll
  for (int o = 32; o >= 1; o >>= 1) ssq += __shfl_xor(ssq, o, 64);
  __shared__ float red[4];
  if ((threadIdx.x & 63) == 0) red[threadIdx.x >> 6] = ssq;
  __syncthreads();
  float tot = red[0] + red[1] + red[2] + red[3];
  float rs = 1.0f / sqrtf(tot / (float)L + 1e-6f);
  for (int c = threadIdx.x; c < nch; c += 256) {
    sx8 v = *(const sx8*)(xr + c * 8);
    sx8 o;
#pragma unroll
    for (int j = 0; j < 8; ++j) o[j] = f2bf(bf2f(v[j]) * rs * w[c * 8 + j]);
    *(sx8*)(orow + c * 8) = o;
  }
}

// ---------------- RoPE q ----------------
__global__ void k_rope_q(short* __restrict__ q, const float* __restrict__ tab) {
  int p = blockIdx.x * blockDim.x + threadIdx.x;
  if (p >= MROWS * NHEADS * 32) return;
  int i = p & 31;
  int h = (p >> 5) & 15;
  int row = p >> 9;
  int pos = row & (SS - 1);
  size_t base = (((size_t)row * NHEADS + h) * QKH) + 128 + 2 * i;
  float c = tab[(pos * 32 + i) * 2], s = tab[(pos * 32 + i) * 2 + 1];
  float x1 = bf2f(q[base]), x2 = bf2f(q[base + 1]);
  q[base]     = f2bf(x1 * c - x2 * s);
  q[base + 1] = f2bf(x1 * s + x2 * c);
}

// ---------------- RoPE k ----------------
__global__ void k_rope_k(const short* __restrict__ kv, short* __restrict__ kr,
                         const float* __restrict__ tab) {
  int p = blockIdx.x * blockDim.x + threadIdx.x;
  if (p >= MROWS * 32) return;
  int i = p & 31;
  int row = p >> 5;
  int pos = row & (SS - 1);
  float c = tab[(pos * 32 + i) * 2], s = tab[(pos * 32 + i) * 2 + 1];
  float x1 = bf2f(kv[(size_t)row * 576 + 512 + 2 * i]);
  float x2 = bf2f(kv[(size_t)row * 576 + 512 + 2 * i + 1]);
  kr[(size_t)row * 64 + 2 * i]     = f2bf(x1 * c - x2 * s);
  kr[(size_t)row * 64 + 2 * i + 1] = f2bf(x1 * s + x2 * c);
}

// ---------------- transpose V ----------------
__global__ __launch_bounds__(256)
void k_vt(const short* __restrict__ kvb, short* __restrict__ vt) {
  int bh = blockIdx.x;
  int t0 = blockIdx.y * 64;
  int b = bh >> 4, h = bh & 15;
  __shared__ short sm[64 * 128];
  int tid = threadIdx.x;
#pragma unroll
  for (int i = 0; i < 4; ++i) {
    int c = tid + 256 * i;
    int tt = c >> 4, d0 = (c & 15) * 8;
    sx8 v = *(const sx8*)(kvb + ((size_t)(b * SS + t0 + tt)) * 4096 + h * 256 + 128 + d0);
    *(sx8*)(sm + tt * 128 + d0) = v;
  }
  __syncthreads();
#pragma unroll
  for (int i = 0; i < 4; ++i) {
    int c = tid + 256 * i;
    int d = c >> 3, tof = (c & 7) * 8;
    sx8 v;
#pragma unroll
    for (int j = 0; j < 8; ++j) v[j] = sm[(tof + j) * 128 + d];
    *(sx8*)(vt + ((size_t)bh * VH + d) * SS + t0 + tof) = v;
  }
}

// ---------------- fused causal attention ----------------
__global__ __launch_bounds__(256, 2)
void k_attn(const short* __restrict__ q, const short* __restrict__ kvb,
            const short* __restrict__ kr, const short* __restrict__ vt,
            short* __restrict__ ao) {
  const int bh = blockIdx.x;
  const int b = bh >> 4, h = bh & 15;
  const int qt0 = blockIdx.y * 64;
  const int tid = threadIdx.x;
  const int lane = tid & 63;
  const int wave = tid >> 6;
  const int g = lane >> 4, r16 = lane & 15;
  const int qg = qt0 + wave * 16 + r16;

  __shared__ short Ks[64 * QKH];
  __shared__ short Vs[VH * 64];

  sx8 qf[6];
  {
    const short* qr = q + (((size_t)(b * SS + qg)) * NHEADS + h) * QKH;
#pragma unroll
    for (int f = 0; f < 6; ++f) qf[f] = ldfrag(qr + f * 32 + 4 * g);
  }

  float mrun = -1e30f, lrun = 0.0f;
  fx4 oacc[8] = {};
  const float scale = 0.07216878364870323f;

  const int ntiles = qt0 / 64 + 1;
  for (int kt = 0; kt < ntiles; ++kt) {
    const int t0 = kt * 64;
#pragma unroll
    for (int i = 0; i < 6; ++i) {
      int cc = tid + 256 * i;
      int row = cc / 24, ch = cc % 24;
      int sc = (ch & 24) | ((ch & 7) ^ (row & 7));
      size_t grow = (size_t)(b * SS + t0 + row);
      const short* src = (sc < 16) ? kvb + grow * 4096 + h * 256 + sc * 8
                                   : kr + grow * 64 + (sc - 16) * 8;
      gl_lds16(src, &Ks[cc * 8]);
    }
#pragma unroll
    for (int i = 0; i < 4; ++i) {
      int cc = tid + 256 * i;
      int row = cc >> 3;
      int sc = (cc & 7) ^ (row & 7);
      gl_lds16(vt + ((size_t)bh * VH + row) * SS + t0 + sc * 8, &Vs[cc * 8]);
    }
    __syncthreads();

    const bool diag = (kt == ntiles - 1);
    float pv[16];
    float tmax = -1e30f;
#pragma unroll
    for (int th = 0; th < 4; ++th) {
      fx4 sacc = {};
#pragma unroll
      for (int f = 0; f < 6; ++f) {
        sx8 kf = ldfrag_swz(Ks, th * 16 + r16, QKH, f * 4, g);
        sacc = __builtin_amdgcn_mfma_f32_16x16x32_bf16(kf, qf[f], sacc, 0, 0, 0);
      }
#pragma unroll
      for (int r = 0; r < 4; ++r) {
        int t = t0 + th * 16 + 4 * g + r;
        float s = sacc[r] * scale;
        if (diag && t > qg) s = -1e30f;
        pv[th * 4 + r] = s;
        tmax = fmaxf(tmax, s);
      }
    }
    tmax = fmaxf(tmax, __shfl_xor(tmax, 16, 64));
    tmax = fmaxf(tmax, __shfl_xor(tmax, 32, 64));
    float mnew = fmaxf(mrun, tmax);
    float corr = __expf(mrun - mnew);
    float psum = 0.f;
#pragma unroll
    for (int j = 0; j < 16; ++j) { pv[j] = __expf(pv[j] - mnew); psum += pv[j]; }
    psum += __shfl_xor(psum, 16, 64);
    psum += __shfl_xor(psum, 32, 64);
    lrun = lrun * corr + psum;
    mrun = mnew;
#pragma unroll
    for (int f8 = 0; f8 < 8; ++f8) oacc[f8] *= corr;

    sx8 pf0, pf1;
#pragma unroll
    for (int j = 0; j < 8; ++j) { pf0[j] = f2bf(pv[j]); pf1[j] = f2bf(pv[8 + j]); }

#pragma unroll
    for (int f8 = 0; f8 < 8; ++f8) {
      sx8 v0 = ldfrag_swz(Vs, f8 * 16 + r16, 64, 0, g);
      sx8 v1 = ldfrag_swz(Vs, f8 * 16 + r16, 64, 4, g);
      oacc[f8] = __builtin_amdgcn_mfma_f32_16x16x32_bf16(v0, pf0, oacc[f8], 0, 0, 0);
      oacc[f8] = __builtin_amdgcn_mfma_f32_16x16x32_bf16(v1, pf1, oacc[f8], 0, 0, 0);
    }
    __syncthreads();
  }

  float inv = 1.0f / lrun;
#pragma unroll
  for (int f8 = 0; f8 < 8; ++f8)
#pragma unroll
    for (int r = 0; r < 4; ++r) {
      int d = f8 * 16 + 4 * g + r;
      ao[(((size_t)(b * SS + qg)) * NHEADS + h) * VH + d] = f2bf(oacc[f8][r] * inv);
    }
}

// ---------------- launcher ----------------
extern "C" void kernel_launch(void* const* d_in, const int* in_sizes, int n_in,
                              void* d_out, int out_size, void* d_ws, size_t ws_size,
                              hipStream_t stream) {
  const float* hs       = (const float*)d_in[0];
  const float* wq_a_w   = (const float*)d_in[2];
  const float* wq_a_b   = (const float*)d_in[3];
  const float* q_norm_w = (const float*)d_in[4];
  const float* wq_b_w   = (const float*)d_in[5];
  const float* wq_b_b   = (const float*)d_in[6];
  const float* wkv_a_w  = (const float*)d_in[7];
  const float* wkv_a_b  = (const float*)d_in[8];
  const float* kv_norm_w= (const float*)d_in[9];
  const float* wkv_b_w  = (const float*)d_in[10];
  const float* wkv_b_b  = (const float*)d_in[11];
  const float* wo_w     = (const float*)d_in[12];
  const float* wo_b     = (const float*)d_in[13];
  float* out = (float*)d_out;

  short* ws0 = (short*)d_ws;
  size_t off = 0;
  short* wqa_bf  = ws0 + off; off += (size_t)QLORA * HID;
  short* wqb_bf  = ws0 + off; off += (size_t)HID * QLORA;
  short* wkva_bf = ws0 + off; off += (size_t)576 * HID;
  short* wkvb_bf = ws0 + off; off += (size_t)4096 * KVLORA;
  short* wo_bf   = ws0 + off; off += (size_t)HID * 2048;
  short* h_bf    = ws0 + off; off += (size_t)MROWS * HID;
  short* qlat    = ws0 + off; off += (size_t)MROWS * QLORA;
  short* qn      = ws0 + off; off += (size_t)MROWS * QLORA;
  short* qb      = ws0 + off; off += (size_t)MROWS * HID;
  short* kv      = ws0 + off; off += (size_t)MROWS * 576;
  short* kr      = ws0 + off; off += (size_t)MROWS * 64;
  short* kvn     = ws0 + off; off += (size_t)MROWS * KVLORA;
  short* kvb     = ws0 + off; off += (size_t)MROWS * 4096;
  short* vtb     = ws0 + off; off += (size_t)BB * NHEADS * VH * SS;
  short* ao      = ws0 + off; off += (size_t)MROWS * 2048;
  float* tab     = (float*)(ws0 + off + (off & 1));

  // 1) bf16 conversions
  k_cvt<<<2048, 256, 0, stream>>>(wq_a_w,  wqa_bf,  (int)((size_t)QLORA * HID / 4));
  k_cvt<<<2048, 256, 0, stream>>>(wq_b_w,  wqb_bf,  (int)((size_t)HID * QLORA / 4));
  k_cvt<<<2048, 256, 0, stream>>>(wkv_a_w, wkva_bf, (int)((size_t)576 * HID / 4));
  k_cvt<<<2048, 256, 0, stream>>>(wkv_b_w, wkvb_bf, (int)((size_t)4096 * KVLORA / 4));
  k_cvt<<<2048, 256, 0, stream>>>(wo_w,    wo_bf,   (int)((size_t)HID * 2048 / 4));
  k_cvt<<<2048, 256, 0, stream>>>(hs,      h_bf,    (int)((size_t)MROWS * HID / 4));
  k_rope_tab<<<(SS * 32 + 255) / 256, 256, 0, stream>>>(tab);

  // 2) merged a-GEMM: qlat (N=1536,K=3072) + kv (N=576,K=3072)
  {
    GemmProb pq{h_bf, wqa_bf,  wq_a_b,  qlat, QLORA, HID, 1};
    GemmProb pk{h_bf, wkva_bf, wkv_a_b, kv,   576,   HID, 1};
    int nb0 = 32 * (QLORA / 128);            // 384
    int nb1 = 32 * ((576 + 127) / 128);      // 160
    k_gemm2<<<nb0 + nb1, 256, 0, stream>>>(pq, pk, nb0);   // 544 blocks
  }

  // 3) norms + rope_k
  k_rmsnorm<<<MROWS, 256, 0, stream>>>(qlat, q_norm_w, qn, QLORA, QLORA);
  k_rope_k<<<(MROWS * 32 + 255) / 256, 256, 0, stream>>>(kv, kr, tab);
  k_rmsnorm<<<MROWS, 256, 0, stream>>>(kv, kv_norm_w, kvn, KVLORA, 576);

  // 4) merged b-GEMM: qb (N=3072,K=1536) + kvb (N=4096,K=512)
  {
    GemmProb pq{qn,  wqb_bf,  wq_b_b,  qb,  HID,  QLORA,  1};
    GemmProb pk{kvn, wkvb_bf, wkv_b_b, kvb, 4096, KVLORA, 1};
    int nb0 = 32 * (HID / 128);              // 768
    int nb1 = 32 * (4096 / 128);             // 1024
    k_gemm2<<<nb0 + nb1, 256, 0, stream>>>(pq, pk, nb0);   // 1792 blocks
  }

  // 5) rope_q + vt
  k_rope_q<<<(MROWS * NHEADS * 32 + 255) / 256, 256, 0, stream>>>(qb, tab);
  k_vt<<<dim3(BB * NHEADS, SS / 64), 256, 0, stream>>>(kvb, vtb);

  // 6) attention
  k_attn<<<dim3(BB * NHEADS, SS / 64), 256, 0, stream>>>(qb, kvb, kr, vtb, ao);

  // 7) output projection (fp32 out)
  {
    GemmProb po{ao, wo_bf, wo_b, out, HID, 2048, 0};
    int nb0 = 32 * (HID / 128);              // 768
    k_gemm2<<<nb0, 256, 0, stream>>>(po, po, nb0);
  }
}